// Round 6
// baseline (514.717 us; speedup 1.0000x reference)
//
#include <hip/hip_runtime.h>

#define DIN  128
#define DOUT 64
#define TN   64    // nodes per gemm block
#define XP   132   // padded X-tile row (floats)
#define NPHASE 8   // = #XCDs; phase p owned by XCD p via blockIdx&7 round-robin
#define SCB  256   // blocks per phase for phased edge kernels
#define NSTATB 400 // stat partial blocks

// ---------- K1: phased histogram — in-degree cnt[0..N), out-degree cnt[N..2N)
// phase = blockIdx&7 -> one XCD owns one node-octile's counters (L2-local atomics).
// Edge-list loads are non-temporal so streaming reads don't evict the counter
// window from L2.
__global__ __launch_bounds__(256) void k_hist(const int* __restrict__ src,
                                              const int* __restrict__ dst,
                                              unsigned* __restrict__ cnt,
                                              int N, int E, int bound) {
    int phase = blockIdx.x & (NPHASE - 1);
    int blk   = blockIdx.x >> 3;
    int lo = phase * bound, hi = lo + bound;
    for (int i = blk * 256 + threadIdx.x; i < E; i += SCB * 256) {
        int d = __builtin_nontemporal_load(dst + i);
        int s = __builtin_nontemporal_load(src + i);
        if (d >= lo && d < hi) atomicAdd(&cnt[d], 1u);
        if (s >= lo && s < hi) atomicAdd(&cnt[N + s], 1u);
    }
}

// ---------- K2: per-block reduce for scan ----------
__global__ __launch_bounds__(256) void k_scan1(const unsigned* __restrict__ cnt,
                                               unsigned* __restrict__ bsums, int n2) {
    __shared__ unsigned s[256];
    int i = blockIdx.x * 256 + threadIdx.x;
    s[threadIdx.x] = (i < n2) ? cnt[i] : 0u;
    __syncthreads();
    for (int st = 128; st > 0; st >>= 1) {
        if (threadIdx.x < st) s[threadIdx.x] += s[threadIdx.x + st];
        __syncthreads();
    }
    if (threadIdx.x == 0) bsums[blockIdx.x] = s[0];
}

// ---------- K3: single-block exclusive scan of block sums (NB <= 1024) ----------
__global__ __launch_bounds__(1024) void k_scan2(unsigned* __restrict__ bsums, int NB) {
    __shared__ unsigned s[1024];
    int tid = threadIdx.x;
    unsigned v = (tid < NB) ? bsums[tid] : 0u;
    s[tid] = v;
    __syncthreads();
    for (int st = 1; st < 1024; st <<= 1) {
        unsigned t = (tid >= st) ? s[tid - st] : 0u;
        __syncthreads();
        s[tid] += t;
        __syncthreads();
    }
    if (tid < NB) bsums[tid] = s[tid] - v;   // exclusive
}

// ---------- K4: block scan + add base -> off, cur; also dinv ----------
__global__ __launch_bounds__(256) void k_scan3(const unsigned* __restrict__ cnt,
                                               const unsigned* __restrict__ bsums,
                                               unsigned* __restrict__ off,
                                               unsigned* __restrict__ cur,
                                               float* __restrict__ dinv,
                                               int N, int n2, unsigned total) {
    __shared__ unsigned s[256];
    int i = blockIdx.x * 256 + threadIdx.x;
    unsigned v = (i < n2) ? cnt[i] : 0u;
    s[threadIdx.x] = v;
    __syncthreads();
    for (int st = 1; st < 256; st <<= 1) {
        unsigned t = (threadIdx.x >= st) ? s[threadIdx.x - st] : 0u;
        __syncthreads();
        s[threadIdx.x] += t;
        __syncthreads();
    }
    unsigned excl = s[threadIdx.x] - v + bsums[blockIdx.x];
    if (i < n2) {
        off[i] = excl;
        cur[i] = excl;
        if (i < N) dinv[i] = rsqrtf((float)v + 1.f);
    }
    if (i == 0) off[n2] = total;
}

// ---------- K5: phased scatter, XCD-owned octiles, nt edge loads ----------
__global__ __launch_bounds__(256) void k_scatter(const int* __restrict__ src,
                                                 const int* __restrict__ dst,
                                                 unsigned* __restrict__ cur,
                                                 int* __restrict__ pay,
                                                 int N, int E, int bound) {
    int phase = blockIdx.x & (NPHASE - 1);
    int blk   = blockIdx.x >> 3;
    int lo = phase * bound, hi = lo + bound;
    for (int i = blk * 256 + threadIdx.x; i < E; i += SCB * 256) {
        int s = __builtin_nontemporal_load(src + i);
        int d = __builtin_nontemporal_load(dst + i);
        if (d >= lo && d < hi) {
            unsigned p1 = atomicAdd(&cur[d], 1u);
            pay[p1] = s;                       // in-CSR stores src id
        }
        if (s >= lo && s < hi) {
            unsigned p2 = atomicAdd(&cur[N + s], 1u);
            pay[p2] = d;                       // out-CSR stores dst id
        }
    }
}

// ---------- K6: h0s = dinv[n] * (x[n] @ W)  register-blocked 4x4 tile GEMM ----------
__global__ __launch_bounds__(256) void k_gemm(const float* __restrict__ x,
                                              const float* __restrict__ W,
                                              const float* __restrict__ dinv,
                                              float* __restrict__ h0s, int N) {
    __shared__ float Xs[TN * XP];
    __shared__ float Ws[DIN * DOUT];

    for (int i = threadIdx.x; i < DIN * DOUT / 4; i += 256)
        ((float4*)Ws)[i] = ((const float4*)W)[i];

    int base = blockIdx.x * TN;
    int kq = threadIdx.x & 31;
    int rr = threadIdx.x >> 5;
#pragma unroll
    for (int it = 0; it < 8; ++it) {
        int r = rr + it * 8;
        int n = base + r;
        float4 v = make_float4(0.f, 0.f, 0.f, 0.f);
        if (n < N) v = ((const float4*)(x + (size_t)n * DIN))[kq];
        *((float4*)(Xs + r * XP + 4 * kq)) = v;
    }
    __syncthreads();

    int tx = threadIdx.x & 15;
    int ty = threadIdx.x >> 4;
    float acc[4][4] = {};

#pragma unroll 4
    for (int k = 0; k < DIN; k += 4) {
        float4 a0 = *((float4*)(Xs + (4 * ty + 0) * XP + k));
        float4 a1 = *((float4*)(Xs + (4 * ty + 1) * XP + k));
        float4 a2 = *((float4*)(Xs + (4 * ty + 2) * XP + k));
        float4 a3 = *((float4*)(Xs + (4 * ty + 3) * XP + k));
        float4 w0 = *((float4*)(Ws + (k + 0) * DOUT + 4 * tx));
        float4 w1 = *((float4*)(Ws + (k + 1) * DOUT + 4 * tx));
        float4 w2 = *((float4*)(Ws + (k + 2) * DOUT + 4 * tx));
        float4 w3 = *((float4*)(Ws + (k + 3) * DOUT + 4 * tx));
#define ROW(j, aj)                                                             \
        acc[j][0] = fmaf(aj.x, w0.x, fmaf(aj.y, w1.x, fmaf(aj.z, w2.x, fmaf(aj.w, w3.x, acc[j][0])))); \
        acc[j][1] = fmaf(aj.x, w0.y, fmaf(aj.y, w1.y, fmaf(aj.z, w2.y, fmaf(aj.w, w3.y, acc[j][1])))); \
        acc[j][2] = fmaf(aj.x, w0.z, fmaf(aj.y, w1.z, fmaf(aj.z, w2.z, fmaf(aj.w, w3.z, acc[j][2])))); \
        acc[j][3] = fmaf(aj.x, w0.w, fmaf(aj.y, w1.w, fmaf(aj.z, w2.w, fmaf(aj.w, w3.w, acc[j][3]))));
        ROW(0, a0) ROW(1, a1) ROW(2, a2) ROW(3, a3)
#undef ROW
    }

#pragma unroll
    for (int j = 0; j < 4; ++j) {
        int n = base + 4 * ty + j;
        if (n < N) {
            float dv = dinv[n];
            float4 o = make_float4(acc[j][0] * dv, acc[j][1] * dv,
                                   acc[j][2] * dv, acc[j][3] * dv);
            *((float4*)(h0s + (size_t)n * DOUT + 4 * tx)) = o;
        }
    }
}

// ---------- K7: gather agg + fused combine ----------
__global__ __launch_bounds__(256) void k_agg(const unsigned* __restrict__ off,
                                             const int* __restrict__ pay,
                                             const float* __restrict__ dinv,
                                             const float* __restrict__ h0s,
                                             const float* __restrict__ b,
                                             float* __restrict__ h, int N) {
    int wave = threadIdx.x >> 6;
    int lane = threadIdx.x & 63;
    int n = blockIdx.x * 4 + wave;
    if (n >= N) return;
    int beg = off[n], end = off[n + 1];
    float acc = 0.f;
    int i = beg;
    for (; i + 2 <= end; i += 2) {
        int s0 = pay[i], s1 = pay[i + 1];
        float a0 = h0s[(size_t)s0 * DOUT + lane];
        float a1 = h0s[(size_t)s1 * DOUT + lane];
        acc += a0 + a1;
    }
    if (i < end) acc += h0s[(size_t)pay[i] * DOUT + lane];
    h[(size_t)n * DOUT + lane] = dinv[n] * (acc + h0s[(size_t)n * DOUT + lane]) + b[lane];
}

// ---------- K8: gather energy + S ----------
__global__ __launch_bounds__(256) void k_energy(const unsigned* __restrict__ off,
                                                const int* __restrict__ pay,
                                                const float* __restrict__ h,
                                                float* __restrict__ e,
                                                float* __restrict__ S, int N) {
    int wave = threadIdx.x >> 6;
    int lane = threadIdx.x & 63;
    int n = blockIdx.x * 4 + wave;
    if (n >= N) return;
    int beg = off[n], end = off[n + 1];
    float hm = h[(size_t)n * DOUT + lane];
    float Ssum = 0.f, esum = 0.f;
    int i = beg;
    for (; i + 2 <= end; i += 2) {
        int s0 = pay[i], s1 = pay[i + 1];
        float h0v = h[(size_t)s0 * DOUT + lane];
        float h1v = h[(size_t)s1 * DOUT + lane];
        Ssum += h0v + h1v;
        float d0 = hm - h0v, d1 = hm - h1v;
        esum += d0 * d0 + d1 * d1;
    }
    if (i < end) {
        float hv = h[(size_t)pay[i] * DOUT + lane];
        Ssum += hv;
        float d = hm - hv;
        esum += d * d;
    }
#pragma unroll
    for (int o = 32; o > 0; o >>= 1) esum += __shfl_down(esum, o, 64);
    if (lane == 0) e[n] = esum;
    S[(size_t)n * DOUT + lane] = Ssum;
}

// ---------- K9: per-block softmax partials (m, Z, M) ----------
__global__ __launch_bounds__(256) void k_stats1(const float* __restrict__ e,
                                                const float* __restrict__ Tptr,
                                                float* __restrict__ part, int N) {
    float T = *Tptr;
    float m = -3.4e38f;
    int i0 = blockIdx.x * 256 + threadIdx.x;
    int stride = gridDim.x * 256;
    for (int i = i0; i < N; i += stride) m = fmaxf(m, -e[i] / T);
    __shared__ float sm[256];
    sm[threadIdx.x] = m;
    __syncthreads();
    for (int s = 128; s > 0; s >>= 1) {
        if (threadIdx.x < s) sm[threadIdx.x] = fmaxf(sm[threadIdx.x], sm[threadIdx.x + s]);
        __syncthreads();
    }
    float bm = sm[0];
    __syncthreads();
    float z = 0.f, mm = 0.f;
    for (int i = i0; i < N; i += stride) {
        float t = -e[i] / T - bm;
        float w = __expf(t);
        z += w;
        mm += w * t;
    }
    __shared__ float sz[256], sM[256];
    sz[threadIdx.x] = z;
    sM[threadIdx.x] = mm;
    __syncthreads();
    for (int s = 128; s > 0; s >>= 1) {
        if (threadIdx.x < s) {
            sz[threadIdx.x] += sz[threadIdx.x + s];
            sM[threadIdx.x] += sM[threadIdx.x + s];
        }
        __syncthreads();
    }
    if (threadIdx.x == 0) {
        part[blockIdx.x * 3 + 0] = bm;
        part[blockIdx.x * 3 + 1] = sz[0];
        part[blockIdx.x * 3 + 2] = sM[0];
    }
}

// ---------- K10: merge partials with rescaling -> st = {m, Z, M} ----------
__global__ __launch_bounds__(256) void k_stats2(const float* __restrict__ part,
                                                float* __restrict__ st, int P) {
    __shared__ float sm[256];
    float m = -3.4e38f;
    for (int i = threadIdx.x; i < P; i += 256) m = fmaxf(m, part[3 * i]);
    sm[threadIdx.x] = m;
    __syncthreads();
    for (int s = 128; s > 0; s >>= 1) {
        if (threadIdx.x < s) sm[threadIdx.x] = fmaxf(sm[threadIdx.x], sm[threadIdx.x + s]);
        __syncthreads();
    }
    float gm = sm[0];
    __syncthreads();
    float Z = 0.f, M = 0.f;
    for (int i = threadIdx.x; i < P; i += 256) {
        float mb = part[3 * i], zb = part[3 * i + 1], Mb = part[3 * i + 2];
        float d = mb - gm, eb = __expf(d);
        Z += eb * zb;
        M += eb * (Mb + d * zb);
    }
    __shared__ float sz[256], sM2[256];
    sz[threadIdx.x] = Z;
    sM2[threadIdx.x] = M;
    __syncthreads();
    for (int s = 128; s > 0; s >>= 1) {
        if (threadIdx.x < s) {
            sz[threadIdx.x] += sz[threadIdx.x + s];
            sM2[threadIdx.x] += sM2[threadIdx.x + s];
        }
        __syncthreads();
    }
    if (threadIdx.x == 0) {
        st[0] = gm;
        st[1] = sz[0];
        st[2] = sM2[0];
    }
}

// ---------- K11: c_n = p_n * (logp_n + H) ----------
__global__ __launch_bounds__(256) void k_coef(const float* __restrict__ e,
                                              const float* __restrict__ Tptr,
                                              const float* __restrict__ st,
                                              float* __restrict__ c, int N) {
    int n = blockIdx.x * 256 + threadIdx.x;
    if (n >= N) return;
    float T = *Tptr;
    float gm = st[0], Z = st[1], M = st[2];
    float logZ = logf(Z);
    float H = logZ - M / Z;
    float t = -e[n] / T - gm;
    float lp = t - logZ;
    c[n] = expf(lp) * (lp + H);
}

// ---------- K12: out-CSR gather of A,B + fused final ----------
__global__ __launch_bounds__(256) void k_grad_final(const unsigned* __restrict__ off,
                                                    const int* __restrict__ pay,
                                                    const float* __restrict__ c,
                                                    const float* __restrict__ h,
                                                    const float* __restrict__ S,
                                                    const unsigned* __restrict__ cnt,
                                                    const float* __restrict__ wptr,
                                                    float* __restrict__ out, int N) {
    int wave = threadIdx.x >> 6;
    int lane = threadIdx.x & 63;
    int n = blockIdx.x * 4 + wave;
    if (n >= N) return;
    int beg = off[N + n], end = off[N + n + 1];
    float A = 0.f, B = 0.f;
    int i = beg;
    for (; i + 2 <= end; i += 2) {
        int d0 = pay[i], d1 = pay[i + 1];
        float c0 = c[d0], c1 = c[d1];
        B += c0 * h[(size_t)d0 * DOUT + lane] + c1 * h[(size_t)d1 * DOUT + lane];
        A += c0 + c1;
    }
    if (i < end) {
        int d = pay[i];
        float cd = c[d];
        B += cd * h[(size_t)d * DOUT + lane];
        A += cd;
    }
    size_t idx = (size_t)n * DOUT + lane;
    float hm = h[idx];
    float w = *wptr;
    float g = 2.f * c[n] * ((float)cnt[n] * hm - S[idx]) + 2.f * (A * hm - B);
    out[idx] = hm + w * g;
}

extern "C" void kernel_launch(void* const* d_in, const int* in_sizes, int n_in,
                              void* d_out, int out_size, void* d_ws, size_t ws_size,
                              hipStream_t stream) {
    const float* x    = (const float*)d_in[0];
    const int*   ei   = (const int*)d_in[1];
    const float* wptr = (const float*)d_in[2];
    const float* Tptr = (const float*)d_in[3];
    const float* W    = (const float*)d_in[4];
    const float* b    = (const float*)d_in[5];
    float* out = (float*)d_out;

    const int N  = in_sizes[0] / DIN;   // 100000
    const int E  = in_sizes[1] / 2;     // 1000000
    const int NE = N * DOUT;
    const int n2 = 2 * N;
    const int NB = (n2 + 255) / 256;
    const int* src = ei;
    const int* dst = ei + E;

    // workspace layout
    float*    h0s  = (float*)d_ws;                 // NE (reused as S later)
    float*    h    = h0s + NE;                     // NE
    int*      pay  = (int*)(h + NE);               // 2E
    unsigned* cnt  = (unsigned*)(pay + 2 * (size_t)E);  // 2N
    unsigned* off  = cnt + n2;                     // 2N+1
    unsigned* cur  = off + n2 + 1;                 // 2N
    unsigned* bsum = cur + n2;                     // NB (<=1024)
    float*    e    = (float*)(bsum + 1024);        // N
    float*    c    = e + N;                        // N
    float*    dinv = c + N;                        // N
    float*    part = dinv + N;                     // 3*NSTATB
    float*    st   = part + 3 * NSTATB;            // 3
    float*    S    = h0s;                          // reuse after k_agg

    hipMemsetAsync(cnt, 0, (size_t)n2 * 4, stream);

    const int nodeW = (N + 3) / 4;
    const int nodeBlocks = (N + 255) / 256;
    const int bound = (N + NPHASE - 1) / NPHASE;

    k_hist<<<NPHASE * SCB, 256, 0, stream>>>(src, dst, cnt, N, E, bound);
    k_scan1<<<NB, 256, 0, stream>>>(cnt, bsum, n2);
    k_scan2<<<1, 1024, 0, stream>>>(bsum, NB);
    k_scan3<<<NB, 256, 0, stream>>>(cnt, bsum, off, cur, dinv, N, n2, (unsigned)(2 * E));
    k_scatter<<<NPHASE * SCB, 256, 0, stream>>>(src, dst, cur, pay, N, E, bound);
    k_gemm<<<(N + TN - 1) / TN, 256, 0, stream>>>(x, W, dinv, h0s, N);
    k_agg<<<nodeW, 256, 0, stream>>>(off, pay, dinv, h0s, b, h, N);
    k_energy<<<nodeW, 256, 0, stream>>>(off, pay, h, e, S, N);
    k_stats1<<<NSTATB, 256, 0, stream>>>(e, Tptr, part, N);
    k_stats2<<<1, 256, 0, stream>>>(part, st, NSTATB);
    k_coef<<<nodeBlocks, 256, 0, stream>>>(e, Tptr, st, c, N);
    k_grad_final<<<nodeW, 256, 0, stream>>>(off, pay, c, h, S, cnt, wptr, out, N);
}

// Round 7
// 410.973 us; speedup vs baseline: 1.2524x; 1.2524x over previous
//
#include <hip/hip_runtime.h>

#define DIN  128
#define DOUT 64
#define TN   64     // nodes per gemm block
#define XP   132    // padded X-tile row (floats)
#define BW   512    // nodes per bucket (power of 2)
#define BSH  9      // log2(BW)
#define EPC  4096   // edges per chunk
#define NSTATB 400  // stat partial blocks

// ---------- K1: per-chunk, per-bucket histograms for BOTH directions ----------
// counts[j*NC + c]       = #edges in chunk c with dst in bucket j
// counts[M + j*NC + c]   = #edges in chunk c with src in bucket j
__global__ __launch_bounds__(256) void k_countboth(const int* __restrict__ src,
                                                   const int* __restrict__ dst,
                                                   unsigned* __restrict__ counts,
                                                   int NBUK, int NC, int E) {
    __shared__ int h0[256], h1[256];
    for (int j = threadIdx.x; j < NBUK; j += 256) { h0[j] = 0; h1[j] = 0; }
    __syncthreads();
    int start = blockIdx.x * EPC;
    int end = min(start + EPC, E);
    for (int i = start + threadIdx.x; i < end; i += 256) {
        atomicAdd(&h0[dst[i] >> BSH], 1);
        atomicAdd(&h1[src[i] >> BSH], 1);
    }
    __syncthreads();
    int M = NBUK * NC;
    for (int j = threadIdx.x; j < NBUK; j += 256) {
        counts[j * NC + blockIdx.x]     = (unsigned)h0[j];
        counts[M + j * NC + blockIdx.x] = (unsigned)h1[j];
    }
}

// ---------- generic 3-kernel exclusive scan ----------
__global__ __launch_bounds__(256) void k_scanA(const unsigned* __restrict__ data,
                                               unsigned* __restrict__ bsums, int n) {
    __shared__ unsigned s[256];
    int i = blockIdx.x * 256 + threadIdx.x;
    s[threadIdx.x] = (i < n) ? data[i] : 0u;
    __syncthreads();
    for (int st = 128; st > 0; st >>= 1) {
        if (threadIdx.x < st) s[threadIdx.x] += s[threadIdx.x + st];
        __syncthreads();
    }
    if (threadIdx.x == 0) bsums[blockIdx.x] = s[0];
}

__global__ __launch_bounds__(1024) void k_scan2(unsigned* __restrict__ bsums, int NB) {
    __shared__ unsigned s[1024];
    int tid = threadIdx.x;
    unsigned v = (tid < NB) ? bsums[tid] : 0u;
    s[tid] = v;
    __syncthreads();
    for (int st = 1; st < 1024; st <<= 1) {
        unsigned t = (tid >= st) ? s[tid - st] : 0u;
        __syncthreads();
        s[tid] += t;
        __syncthreads();
    }
    if (tid < NB) bsums[tid] = s[tid] - v;   // exclusive
}

__global__ __launch_bounds__(256) void k_scanC(unsigned* __restrict__ data,
                                               const unsigned* __restrict__ bsums, int n) {
    __shared__ unsigned s[256];
    int i = blockIdx.x * 256 + threadIdx.x;
    unsigned v = (i < n) ? data[i] : 0u;
    s[threadIdx.x] = v;
    __syncthreads();
    for (int st = 1; st < 256; st <<= 1) {
        unsigned t = (threadIdx.x >= st) ? s[threadIdx.x - st] : 0u;
        __syncthreads();
        s[threadIdx.x] += t;
        __syncthreads();
    }
    if (i < n) data[i] = s[threadIdx.x] - v + bsums[blockIdx.x];
}

// ---------- K5: bucket-major reorder (coalesced block-private segments) ----------
__global__ __launch_bounds__(256) void k_bucket(const int* __restrict__ key,
                                                const int* __restrict__ other,
                                                const unsigned* __restrict__ counts,
                                                int dirOff, unsigned dirBase,
                                                int2* __restrict__ bucketed,
                                                int NBUK, int NC, int E) {
    __shared__ int cur[256];
    for (int j = threadIdx.x; j < NBUK; j += 256)
        cur[j] = (int)(counts[dirOff + j * NC + blockIdx.x] - dirBase);
    __syncthreads();
    int start = blockIdx.x * EPC;
    int end = min(start + EPC, E);
    for (int i = start + threadIdx.x; i < end; i += 256) {
        int k = key[i], o = other[i];
        int pos = atomicAdd(&cur[k >> BSH], 1);
        bucketed[pos] = make_int2(k, o);
    }
}

// ---------- K6: per-bucket CSR finalize — degrees, offsets, private scatter ----------
__global__ __launch_bounds__(256) void k_csr(const int2* __restrict__ bucketed,
                                             const unsigned* __restrict__ counts,
                                             unsigned* __restrict__ off,
                                             int* __restrict__ pay,
                                             unsigned* __restrict__ cnt,
                                             float* __restrict__ dinv,
                                             int dirOff, unsigned dirBase,
                                             int NBUK, int NC, int N, int E) {
    __shared__ int sH[BW];
    __shared__ int sS[2][BW];
    __shared__ int sC[BW];
    int b = blockIdx.x;
    int base = (int)(counts[dirOff + b * NC] - dirBase);
    int end  = (b + 1 < NBUK) ? (int)(counts[dirOff + (b + 1) * NC] - dirBase) : E;

    for (int j = threadIdx.x; j < BW; j += 256) sH[j] = 0;
    __syncthreads();
    for (int i = base + threadIdx.x; i < end; i += 256)
        atomicAdd(&sH[bucketed[i].x & (BW - 1)], 1);
    __syncthreads();
    for (int j = threadIdx.x; j < BW; j += 256) sS[0][j] = sH[j];
    __syncthreads();
    int pin = 0;
    for (int st = 1; st < BW; st <<= 1) {
        for (int j = threadIdx.x; j < BW; j += 256) {
            int v = sS[pin][j];
            if (j >= st) v += sS[pin][j - st];
            sS[pin ^ 1][j] = v;
        }
        __syncthreads();
        pin ^= 1;
    }
    int lo = b * BW;
    for (int j = threadIdx.x; j < BW; j += 256) {
        int excl = j ? sS[pin][j - 1] : 0;
        sC[j] = excl;
        int n = lo + j;
        if (n < N) {
            off[n] = (unsigned)(base + excl);
            if (cnt) {
                cnt[n] = (unsigned)sH[j];
                dinv[n] = rsqrtf((float)sH[j] + 1.f);
            }
        }
    }
    if (threadIdx.x == 0 && b == NBUK - 1) off[N] = (unsigned)E;
    __syncthreads();
    for (int i = base + threadIdx.x; i < end; i += 256) {
        int2 p = bucketed[i];
        int pos = base + atomicAdd(&sC[p.x & (BW - 1)], 1);
        pay[pos] = p.y;
    }
}

// ---------- K7: h0s = dinv[n] * (x[n] @ W)  register-blocked 4x4 tile GEMM ----------
__global__ __launch_bounds__(256) void k_gemm(const float* __restrict__ x,
                                              const float* __restrict__ W,
                                              const float* __restrict__ dinv,
                                              float* __restrict__ h0s, int N) {
    __shared__ float Xs[TN * XP];
    __shared__ float Ws[DIN * DOUT];

    for (int i = threadIdx.x; i < DIN * DOUT / 4; i += 256)
        ((float4*)Ws)[i] = ((const float4*)W)[i];

    int base = blockIdx.x * TN;
    int kq = threadIdx.x & 31;
    int rr = threadIdx.x >> 5;
#pragma unroll
    for (int it = 0; it < 8; ++it) {
        int r = rr + it * 8;
        int n = base + r;
        float4 v = make_float4(0.f, 0.f, 0.f, 0.f);
        if (n < N) v = ((const float4*)(x + (size_t)n * DIN))[kq];
        *((float4*)(Xs + r * XP + 4 * kq)) = v;
    }
    __syncthreads();

    int tx = threadIdx.x & 15;
    int ty = threadIdx.x >> 4;
    float acc[4][4] = {};

#pragma unroll 4
    for (int k = 0; k < DIN; k += 4) {
        float4 a0 = *((float4*)(Xs + (4 * ty + 0) * XP + k));
        float4 a1 = *((float4*)(Xs + (4 * ty + 1) * XP + k));
        float4 a2 = *((float4*)(Xs + (4 * ty + 2) * XP + k));
        float4 a3 = *((float4*)(Xs + (4 * ty + 3) * XP + k));
        float4 w0 = *((float4*)(Ws + (k + 0) * DOUT + 4 * tx));
        float4 w1 = *((float4*)(Ws + (k + 1) * DOUT + 4 * tx));
        float4 w2 = *((float4*)(Ws + (k + 2) * DOUT + 4 * tx));
        float4 w3 = *((float4*)(Ws + (k + 3) * DOUT + 4 * tx));
#define ROW(j, aj)                                                             \
        acc[j][0] = fmaf(aj.x, w0.x, fmaf(aj.y, w1.x, fmaf(aj.z, w2.x, fmaf(aj.w, w3.x, acc[j][0])))); \
        acc[j][1] = fmaf(aj.x, w0.y, fmaf(aj.y, w1.y, fmaf(aj.z, w2.y, fmaf(aj.w, w3.y, acc[j][1])))); \
        acc[j][2] = fmaf(aj.x, w0.z, fmaf(aj.y, w1.z, fmaf(aj.z, w2.z, fmaf(aj.w, w3.z, acc[j][2])))); \
        acc[j][3] = fmaf(aj.x, w0.w, fmaf(aj.y, w1.w, fmaf(aj.z, w2.w, fmaf(aj.w, w3.w, acc[j][3]))));
        ROW(0, a0) ROW(1, a1) ROW(2, a2) ROW(3, a3)
#undef ROW
    }

#pragma unroll
    for (int j = 0; j < 4; ++j) {
        int n = base + 4 * ty + j;
        if (n < N) {
            float dv = dinv[n];
            float4 o = make_float4(acc[j][0] * dv, acc[j][1] * dv,
                                   acc[j][2] * dv, acc[j][3] * dv);
            *((float4*)(h0s + (size_t)n * DOUT + 4 * tx)) = o;
        }
    }
}

// ---------- K8: gather agg + fused combine ----------
__global__ __launch_bounds__(256) void k_agg(const unsigned* __restrict__ off,
                                             const int* __restrict__ pay,
                                             const float* __restrict__ dinv,
                                             const float* __restrict__ h0s,
                                             const float* __restrict__ b,
                                             float* __restrict__ h, int N) {
    int wave = threadIdx.x >> 6;
    int lane = threadIdx.x & 63;
    int n = blockIdx.x * 4 + wave;
    if (n >= N) return;
    int beg = off[n], end = off[n + 1];
    float acc = 0.f;
    int i = beg;
    for (; i + 2 <= end; i += 2) {
        int s0 = pay[i], s1 = pay[i + 1];
        float a0 = h0s[(size_t)s0 * DOUT + lane];
        float a1 = h0s[(size_t)s1 * DOUT + lane];
        acc += a0 + a1;
    }
    if (i < end) acc += h0s[(size_t)pay[i] * DOUT + lane];
    h[(size_t)n * DOUT + lane] = dinv[n] * (acc + h0s[(size_t)n * DOUT + lane]) + b[lane];
}

// ---------- K9: gather energy + S ----------
__global__ __launch_bounds__(256) void k_energy(const unsigned* __restrict__ off,
                                                const int* __restrict__ pay,
                                                const float* __restrict__ h,
                                                float* __restrict__ e,
                                                float* __restrict__ S, int N) {
    int wave = threadIdx.x >> 6;
    int lane = threadIdx.x & 63;
    int n = blockIdx.x * 4 + wave;
    if (n >= N) return;
    int beg = off[n], end = off[n + 1];
    float hm = h[(size_t)n * DOUT + lane];
    float Ssum = 0.f, esum = 0.f;
    int i = beg;
    for (; i + 2 <= end; i += 2) {
        int s0 = pay[i], s1 = pay[i + 1];
        float h0v = h[(size_t)s0 * DOUT + lane];
        float h1v = h[(size_t)s1 * DOUT + lane];
        Ssum += h0v + h1v;
        float d0 = hm - h0v, d1 = hm - h1v;
        esum += d0 * d0 + d1 * d1;
    }
    if (i < end) {
        float hv = h[(size_t)pay[i] * DOUT + lane];
        Ssum += hv;
        float d = hm - hv;
        esum += d * d;
    }
#pragma unroll
    for (int o = 32; o > 0; o >>= 1) esum += __shfl_down(esum, o, 64);
    if (lane == 0) e[n] = esum;
    S[(size_t)n * DOUT + lane] = Ssum;
}

// ---------- K10: per-block softmax partials (m, Z, M) ----------
__global__ __launch_bounds__(256) void k_stats1(const float* __restrict__ e,
                                                const float* __restrict__ Tptr,
                                                float* __restrict__ part, int N) {
    float T = *Tptr;
    float m = -3.4e38f;
    int i0 = blockIdx.x * 256 + threadIdx.x;
    int stride = gridDim.x * 256;
    for (int i = i0; i < N; i += stride) m = fmaxf(m, -e[i] / T);
    __shared__ float sm[256];
    sm[threadIdx.x] = m;
    __syncthreads();
    for (int s = 128; s > 0; s >>= 1) {
        if (threadIdx.x < s) sm[threadIdx.x] = fmaxf(sm[threadIdx.x], sm[threadIdx.x + s]);
        __syncthreads();
    }
    float bm = sm[0];
    __syncthreads();
    float z = 0.f, mm = 0.f;
    for (int i = i0; i < N; i += stride) {
        float t = -e[i] / T - bm;
        float w = __expf(t);
        z += w;
        mm += w * t;
    }
    __shared__ float sz[256], sM[256];
    sz[threadIdx.x] = z;
    sM[threadIdx.x] = mm;
    __syncthreads();
    for (int s = 128; s > 0; s >>= 1) {
        if (threadIdx.x < s) {
            sz[threadIdx.x] += sz[threadIdx.x + s];
            sM[threadIdx.x] += sM[threadIdx.x + s];
        }
        __syncthreads();
    }
    if (threadIdx.x == 0) {
        part[blockIdx.x * 3 + 0] = bm;
        part[blockIdx.x * 3 + 1] = sz[0];
        part[blockIdx.x * 3 + 2] = sM[0];
    }
}

// ---------- K11: merge partials -> st = {m, Z, M} ----------
__global__ __launch_bounds__(256) void k_stats2(const float* __restrict__ part,
                                                float* __restrict__ st, int P) {
    __shared__ float sm[256];
    float m = -3.4e38f;
    for (int i = threadIdx.x; i < P; i += 256) m = fmaxf(m, part[3 * i]);
    sm[threadIdx.x] = m;
    __syncthreads();
    for (int s = 128; s > 0; s >>= 1) {
        if (threadIdx.x < s) sm[threadIdx.x] = fmaxf(sm[threadIdx.x], sm[threadIdx.x + s]);
        __syncthreads();
    }
    float gm = sm[0];
    __syncthreads();
    float Z = 0.f, M = 0.f;
    for (int i = threadIdx.x; i < P; i += 256) {
        float mb = part[3 * i], zb = part[3 * i + 1], Mb = part[3 * i + 2];
        float d = mb - gm, eb = __expf(d);
        Z += eb * zb;
        M += eb * (Mb + d * zb);
    }
    __shared__ float sz[256], sM2[256];
    sz[threadIdx.x] = Z;
    sM2[threadIdx.x] = M;
    __syncthreads();
    for (int s = 128; s > 0; s >>= 1) {
        if (threadIdx.x < s) {
            sz[threadIdx.x] += sz[threadIdx.x + s];
            sM2[threadIdx.x] += sM2[threadIdx.x + s];
        }
        __syncthreads();
    }
    if (threadIdx.x == 0) {
        st[0] = gm;
        st[1] = sz[0];
        st[2] = sM2[0];
    }
}

// ---------- K12: c_n = p_n * (logp_n + H) ----------
__global__ __launch_bounds__(256) void k_coef(const float* __restrict__ e,
                                              const float* __restrict__ Tptr,
                                              const float* __restrict__ st,
                                              float* __restrict__ c, int N) {
    int n = blockIdx.x * 256 + threadIdx.x;
    if (n >= N) return;
    float T = *Tptr;
    float gm = st[0], Z = st[1], M = st[2];
    float logZ = logf(Z);
    float H = logZ - M / Z;
    float t = -e[n] / T - gm;
    float lp = t - logZ;
    c[n] = expf(lp) * (lp + H);
}

// ---------- K13: out-CSR gather of A,B + fused final ----------
__global__ __launch_bounds__(256) void k_grad_final(const unsigned* __restrict__ off,
                                                    const int* __restrict__ pay,
                                                    const float* __restrict__ c,
                                                    const float* __restrict__ h,
                                                    const float* __restrict__ S,
                                                    const unsigned* __restrict__ cnt,
                                                    const float* __restrict__ wptr,
                                                    float* __restrict__ out, int N) {
    int wave = threadIdx.x >> 6;
    int lane = threadIdx.x & 63;
    int n = blockIdx.x * 4 + wave;
    if (n >= N) return;
    int beg = off[n], end = off[n + 1];
    float A = 0.f, B = 0.f;
    int i = beg;
    for (; i + 2 <= end; i += 2) {
        int d0 = pay[i], d1 = pay[i + 1];
        float c0 = c[d0], c1 = c[d1];
        B += c0 * h[(size_t)d0 * DOUT + lane] + c1 * h[(size_t)d1 * DOUT + lane];
        A += c0 + c1;
    }
    if (i < end) {
        int d = pay[i];
        float cd = c[d];
        B += cd * h[(size_t)d * DOUT + lane];
        A += cd;
    }
    size_t idx = (size_t)n * DOUT + lane;
    float hm = h[idx];
    float w = *wptr;
    float g = 2.f * c[n] * ((float)cnt[n] * hm - S[idx]) + 2.f * (A * hm - B);
    out[idx] = hm + w * g;
}

extern "C" void kernel_launch(void* const* d_in, const int* in_sizes, int n_in,
                              void* d_out, int out_size, void* d_ws, size_t ws_size,
                              hipStream_t stream) {
    const float* x    = (const float*)d_in[0];
    const int*   ei   = (const int*)d_in[1];
    const float* wptr = (const float*)d_in[2];
    const float* Tptr = (const float*)d_in[3];
    const float* W    = (const float*)d_in[4];
    const float* b    = (const float*)d_in[5];
    float* out = (float*)d_out;

    const int N  = in_sizes[0] / DIN;   // 100000
    const int E  = in_sizes[1] / 2;     // 1000000
    const int NE = N * DOUT;
    const int* src = ei;
    const int* dst = ei + E;

    const int NBUK = (N + BW - 1) / BW;         // 196
    const int NC   = (E + EPC - 1) / EPC;       // 245
    const int M    = NBUK * NC;
    const int M2   = 2 * M;
    const int NBs  = (M2 + 255) / 256;          // <= 1024

    // workspace layout
    float*    h0s  = (float*)d_ws;                    // NE (reused as S later)
    float*    h    = h0s + NE;                        // NE
    int2*     bkt  = (int2*)(h + NE);                 // E int2 (8 MB, reused per dir)
    int*      pay1 = (int*)(bkt + E);                 // E (in-CSR payload: src ids)
    int*      pay2 = pay1 + E;                        // E (out-CSR payload: dst ids)
    unsigned* counts = (unsigned*)(pay2 + E);         // 2*M
    unsigned* bsum = counts + M2;                     // <=1024
    unsigned* off1 = bsum + 1024;                     // N+1
    unsigned* off2 = off1 + N + 1;                    // N+1
    unsigned* cnt  = off2 + N + 1;                    // N
    float*    e    = (float*)(cnt + N);               // N
    float*    c    = e + N;                           // N
    float*    dinv = c + N;                           // N
    float*    part = dinv + N;                        // 3*NSTATB
    float*    st   = part + 3 * NSTATB;               // 3
    float*    S    = h0s;                             // reuse after k_agg

    const int nodeW = (N + 3) / 4;
    const int nodeBlocks = (N + 255) / 256;

    // build both direction counts + one combined scan
    k_countboth<<<NC, 256, 0, stream>>>(src, dst, counts, NBUK, NC, E);
    k_scanA<<<NBs, 256, 0, stream>>>(counts, bsum, M2);
    k_scan2<<<1, 1024, 0, stream>>>(bsum, NBs);
    k_scanC<<<NBs, 256, 0, stream>>>(counts, bsum, M2);

    // direction 0: in-CSR (key=dst, payload=src) -> off1/pay1 + cnt/dinv
    k_bucket<<<NC, 256, 0, stream>>>(dst, src, counts, 0, 0u, bkt, NBUK, NC, E);
    k_csr<<<NBUK, 256, 0, stream>>>(bkt, counts, off1, pay1, cnt, dinv,
                                    0, 0u, NBUK, NC, N, E);
    // direction 1: out-CSR (key=src, payload=dst) -> off2/pay2
    k_bucket<<<NC, 256, 0, stream>>>(src, dst, counts, M, (unsigned)E, bkt, NBUK, NC, E);
    k_csr<<<NBUK, 256, 0, stream>>>(bkt, counts, off2, pay2, nullptr, nullptr,
                                    M, (unsigned)E, NBUK, NC, N, E);

    k_gemm<<<(N + TN - 1) / TN, 256, 0, stream>>>(x, W, dinv, h0s, N);
    k_agg<<<nodeW, 256, 0, stream>>>(off1, pay1, dinv, h0s, b, h, N);
    k_energy<<<nodeW, 256, 0, stream>>>(off1, pay1, h, e, S, N);
    k_stats1<<<NSTATB, 256, 0, stream>>>(e, Tptr, part, N);
    k_stats2<<<1, 256, 0, stream>>>(part, st, NSTATB);
    k_coef<<<nodeBlocks, 256, 0, stream>>>(e, Tptr, st, c, N);
    k_grad_final<<<nodeW, 256, 0, stream>>>(off2, pay2, c, h, S, cnt, wptr, out, N);
}